// Round 1
// baseline (718.705 us; speedup 1.0000x reference)
//
#include <hip/hip_runtime.h>
#include <math.h>

// Problem constants (match setup_inputs)
constexpr int N = 64;
constexpr int P = 24564;
constexpr int M = 16;
constexpr int C = 21;
constexpr float THRESH = 0.5f;

// ---- workspace layout (bytes) ----
constexpr size_t OFF_LOSS_L = 0;                               // double[1]
constexpr size_t OFF_NUMPOS = 16;                              // int[N]
constexpr size_t OFF_SPOS   = OFF_NUMPOS + (size_t)N * 4;      // float[N]
constexpr size_t OFF_LCROW  = OFF_SPOS + (size_t)N * 4;        // float[N]
constexpr size_t OFF_BPK    = ((OFF_LCROW + (size_t)N * 4 + 15) / 16) * 16; // ull[N*M]
constexpr size_t OFF_ZERO_END = OFF_BPK + (size_t)N * M * 8;   // zeroed each launch
constexpr size_t OFF_BTO   = ((OFF_ZERO_END + 15) / 16) * 16;  // float[N*P]
constexpr size_t OFF_BTI   = OFF_BTO + (size_t)N * P * 4;      // int[N*P]
constexpr size_t OFF_MINED = OFF_BTI + (size_t)N * P * 4;      // float[N*P]
constexpr size_t WS_NEEDED = OFF_MINED + (size_t)N * P * 4;

__device__ __forceinline__ float smooth_l1(float d) {
    float a = fabsf(d);
    return (a < 1.0f) ? 0.5f * d * d : (a - 0.5f);
}

// Kernel A: per-(n,p) jaccard vs all truths; best-truth per prior; best-prior per truth.
__global__ __launch_bounds__(256) void k_match(
    const float* __restrict__ priors, const float* __restrict__ targets,
    float* __restrict__ bto, int* __restrict__ bti,
    unsigned long long* __restrict__ bpk) {
    const int n = blockIdx.y;
    const int tid = threadIdx.x;
    const int p = blockIdx.x * 256 + tid;
    __shared__ float st[M * 5];
    __shared__ unsigned long long sbp[M];
    if (tid < M * 5) st[tid] = targets[(size_t)n * M * 5 + tid];
    if (tid < M) sbp[tid] = 0ull;
    __syncthreads();
    if (p < P) {
        float4 pr = reinterpret_cast<const float4*>(priors)[p];
        float bx1 = pr.x - pr.z * 0.5f, by1 = pr.y - pr.w * 0.5f;
        float bx2 = pr.x + pr.z * 0.5f, by2 = pr.y + pr.w * 0.5f;
        float area_b = (bx2 - bx1) * (by2 - by1);
        float bestv = -1.0f;
        int bestm = 0;
        #pragma unroll
        for (int m = 0; m < M; ++m) {
            float tx1 = st[m * 5 + 0], ty1 = st[m * 5 + 1];
            float tx2 = st[m * 5 + 2], ty2 = st[m * 5 + 3];
            float ix = fminf(tx2, bx2) - fmaxf(tx1, bx1);
            ix = fmaxf(ix, 0.0f);
            float iy = fminf(ty2, by2) - fmaxf(ty1, by1);
            iy = fmaxf(iy, 0.0f);
            float inter = ix * iy;
            float area_a = (tx2 - tx1) * (ty2 - ty1);
            float ov = inter / (area_a + area_b - inter);
            if (ov > bestv) { bestv = ov; bestm = m; }  // first-index tie-break
            // pack (value, inverted index): larger key == better (higher ov, then smaller p)
            unsigned long long key =
                ((unsigned long long)__float_as_uint(ov) << 32) |
                (unsigned long long)(0xFFFFFFFFu - (unsigned)p);
            atomicMax(&sbp[m], key);
        }
        bto[(size_t)n * P + p] = bestv;
        bti[(size_t)n * P + p] = bestm;
    }
    __syncthreads();
    if (tid < M) atomicMax(&bpk[(size_t)n * M + tid], sbp[tid]);
}

// Kernel B: force each truth's best prior to be a positive match; last write (highest m) wins
// to match numpy duplicate-index assignment semantics.
__global__ void k_force(float* __restrict__ bto, int* __restrict__ bti,
                        const unsigned long long* __restrict__ bpk) {
    int n = threadIdx.x;
    if (n < N) {
        for (int m = 0; m < M; ++m) {
            unsigned int low = (unsigned int)(bpk[(size_t)n * M + m] & 0xFFFFFFFFull);
            int bp = (int)(0xFFFFFFFFu - low);
            bto[(size_t)n * P + bp] = 2.0f;
            bti[(size_t)n * P + bp] = m;
        }
    }
}

// Kernel C: encode + smooth-L1 (pos-masked), logsumexp, conf loss, mined values,
// per-row num_pos and sum-of-pos conf loss, global loc loss.
__global__ __launch_bounds__(256) void k_loss(
    const float* __restrict__ loc, const float* __restrict__ conf,
    const float* __restrict__ priors, const float* __restrict__ targets,
    const float* __restrict__ bto, const int* __restrict__ bti,
    float* __restrict__ mined, double* __restrict__ loss_l_acc,
    int* __restrict__ num_pos, float* __restrict__ s_pos) {
    const int n = blockIdx.y;
    const int p0 = blockIdx.x * 256;
    const int tid = threadIdx.x;
    __shared__ float sc[256 * C];
    __shared__ float st[M * 5];
    __shared__ float wll[4], wsp[4];
    __shared__ int wnp[4];

    {   // coalesced stage of this block's conf tile
        const float* src = conf + (size_t)n * P * C + (size_t)p0 * C;
        int cnt = min(256, P - p0) * C;
        for (int i = tid; i < cnt; i += 256) sc[i] = src[i];
    }
    if (tid < M * 5) st[tid] = targets[(size_t)n * M * 5 + tid];
    __syncthreads();

    float my_ll = 0.0f, my_sp = 0.0f;
    int my_np = 0;
    const int p = p0 + tid;
    if (p < P) {
        float ov = bto[(size_t)n * P + p];
        int bt = bti[(size_t)n * P + p];
        bool pos = !(ov < THRESH);
        float mx1 = st[bt * 5 + 0], my1 = st[bt * 5 + 1];
        float mx2 = st[bt * 5 + 2], my2 = st[bt * 5 + 3];
        int conf_t = pos ? ((int)st[bt * 5 + 4] + 1) : 0;

        if (pos) {
            float4 pr = reinterpret_cast<const float4*>(priors)[p];
            float gcx = ((mx1 + mx2) * 0.5f - pr.x) / (0.1f * pr.z);
            float gcy = ((my1 + my2) * 0.5f - pr.y) / (0.1f * pr.w);
            float gw = logf((mx2 - mx1) / pr.z) / 0.2f;
            float gh = logf((my2 - my1) / pr.w) / 0.2f;
            float4 ld = reinterpret_cast<const float4*>(loc)[(size_t)n * P + p];
            my_ll = smooth_l1(ld.x - gcx) + smooth_l1(ld.y - gcy) +
                    smooth_l1(ld.z - gw) + smooth_l1(ld.w - gh);
            my_np = 1;
        }
        // logsumexp over 21 classes (max-shifted)
        float cv[C];
        #pragma unroll
        for (int c = 0; c < C; ++c) cv[c] = sc[tid * C + c];
        float mx = cv[0];
        #pragma unroll
        for (int c = 1; c < C; ++c) mx = fmaxf(mx, cv[c]);
        float s = 0.0f;
        #pragma unroll
        for (int c = 0; c < C; ++c) s += expf(cv[c] - mx);
        float lse = mx + logf(s);
        float lc = lse - cv[conf_t];
        if (pos) my_sp = lc;
        mined[(size_t)n * P + p] = pos ? 0.0f : lc;
    }

    // block reduce
    for (int off = 32; off > 0; off >>= 1) {
        my_ll += __shfl_down(my_ll, off);
        my_sp += __shfl_down(my_sp, off);
        my_np += __shfl_down(my_np, off);
    }
    int wave = tid >> 6, lane = tid & 63;
    if (lane == 0) { wll[wave] = my_ll; wsp[wave] = my_sp; wnp[wave] = my_np; }
    __syncthreads();
    if (tid == 0) {
        float ll = wll[0] + wll[1] + wll[2] + wll[3];
        float sp = wsp[0] + wsp[1] + wsp[2] + wsp[3];
        int np_ = wnp[0] + wnp[1] + wnp[2] + wnp[3];
        if (ll != 0.0f) atomicAdd(loss_l_acc, (double)ll);
        if (np_) atomicAdd(&num_pos[n], np_);
        if (sp != 0.0f) atomicAdd(&s_pos[n], sp);
    }
}

// Kernel D: per row, K = min(3*num_pos, P-1); T = K-th largest mined (radix select on
// float bits, valid since mined >= 0); loss_c_row = s_pos + sum(mined>T) + (K - cnt>T)*T.
__global__ __launch_bounds__(256) void k_select(
    const float* __restrict__ mined, const int* __restrict__ num_pos,
    const float* __restrict__ s_pos, float* __restrict__ lcrow) {
    const int n = blockIdx.x;
    const int tid = threadIdx.x;
    const float* row = mined + (size_t)n * P;
    __shared__ unsigned int hist[256];
    __shared__ unsigned int s_prefix;
    __shared__ int s_remK;
    __shared__ float wsg[4];
    __shared__ int wcg[4];

    const int K = min(3 * num_pos[n], P - 1);
    if (K <= 0) {
        if (tid == 0) lcrow[n] = s_pos[n];
        return;
    }
    unsigned int prefix = 0;
    int remK = K;
    for (int pass = 0; pass < 4; ++pass) {
        const int shift = 24 - pass * 8;
        hist[tid] = 0;
        __syncthreads();
        const unsigned int himask = (pass == 0) ? 0u : (0xFFFFFFFFu << (shift + 8));
        for (int i = tid; i < P; i += 256) {
            unsigned int key = __float_as_uint(row[i]);
            if ((key & himask) == prefix)
                atomicAdd(&hist[(key >> shift) & 0xFFu], 1u);
        }
        __syncthreads();
        if (tid == 0) {
            unsigned int cum = 0;
            int b = 255;
            for (; b >= 0; --b) {
                unsigned int c = hist[b];
                if (cum + c >= (unsigned)remK) break;
                cum += c;
            }
            if (b < 0) b = 0;  // defensive; invariant guarantees b >= 0
            s_prefix = prefix | ((unsigned)b << shift);
            s_remK = remK - (int)cum;
        }
        __syncthreads();
        prefix = s_prefix;
        remK = s_remK;
        __syncthreads();
    }
    const float T = __uint_as_float(prefix);
    float sgt = 0.0f;
    int cgt = 0;
    for (int i = tid; i < P; i += 256) {
        float v = row[i];
        if (v > T) { sgt += v; cgt++; }
    }
    for (int off = 32; off > 0; off >>= 1) {
        sgt += __shfl_down(sgt, off);
        cgt += __shfl_down(cgt, off);
    }
    int wave = tid >> 6, lane = tid & 63;
    if (lane == 0) { wsg[wave] = sgt; wcg[wave] = cgt; }
    __syncthreads();
    if (tid == 0) {
        float S = wsg[0] + wsg[1] + wsg[2] + wsg[3];
        int Cg = wcg[0] + wcg[1] + wcg[2] + wcg[3];
        lcrow[n] = s_pos[n] + S + (float)(K - Cg) * T;
    }
}

// Kernel E: finalize.
__global__ void k_final(const double* __restrict__ loss_l_acc,
                        const int* __restrict__ num_pos,
                        const float* __restrict__ lcrow,
                        float* __restrict__ out) {
    int t = threadIdx.x;  // 64 threads = 1 wave
    int npv = num_pos[t];
    float lcv = lcrow[t];
    for (int off = 32; off > 0; off >>= 1) {
        npv += __shfl_down(npv, off);
        lcv += __shfl_down(lcv, off);
    }
    if (t == 0) {
        float nf = (float)npv;
        out[0] = (float)(*loss_l_acc) / nf;
        out[1] = lcv / nf;
    }
}

extern "C" void kernel_launch(void* const* d_in, const int* in_sizes, int n_in,
                              void* d_out, int out_size, void* d_ws, size_t ws_size,
                              hipStream_t stream) {
    const float* loc = (const float*)d_in[0];
    const float* conf = (const float*)d_in[1];
    const float* priors = (const float*)d_in[2];
    const float* targets = (const float*)d_in[3];

    if (ws_size < WS_NEEDED) return;  // workspace too small; fail loudly at validation

    char* ws = (char*)d_ws;
    double* loss_l_acc = (double*)(ws + OFF_LOSS_L);
    int* num_pos = (int*)(ws + OFF_NUMPOS);
    float* s_pos = (float*)(ws + OFF_SPOS);
    float* lcrow = (float*)(ws + OFF_LCROW);
    unsigned long long* bpk = (unsigned long long*)(ws + OFF_BPK);
    float* bto = (float*)(ws + OFF_BTO);
    int* bti = (int*)(ws + OFF_BTI);
    float* mined = (float*)(ws + OFF_MINED);

    hipMemsetAsync(ws, 0, OFF_ZERO_END, stream);

    dim3 grid((P + 255) / 256, N);
    k_match<<<grid, 256, 0, stream>>>(priors, targets, bto, bti, bpk);
    k_force<<<1, 64, 0, stream>>>(bto, bti, bpk);
    k_loss<<<grid, 256, 0, stream>>>(loc, conf, priors, targets, bto, bti,
                                     mined, loss_l_acc, num_pos, s_pos);
    k_select<<<N, 256, 0, stream>>>(mined, num_pos, s_pos, lcrow);
    k_final<<<1, 64, 0, stream>>>(loss_l_acc, num_pos, lcrow, (float*)d_out);
}

// Round 2
// 427.533 us; speedup vs baseline: 1.6811x; 1.6811x over previous
//
#include <hip/hip_runtime.h>
#include <math.h>

// Problem constants (match setup_inputs)
constexpr int N = 64;
constexpr int P = 24564;
constexpr int M = 16;
constexpr int C = 21;
constexpr float THRESH = 0.5f;

// ---- workspace layout (bytes) ----
constexpr size_t OFF_LOSS_L = 0;                               // double[1]
constexpr size_t OFF_NUMPOS = 16;                              // int[N]
constexpr size_t OFF_SPOS   = OFF_NUMPOS + (size_t)N * 4;      // float[N]
constexpr size_t OFF_LCROW  = OFF_SPOS + (size_t)N * 4;        // float[N]
constexpr size_t OFF_BPK    = ((OFF_LCROW + (size_t)N * 4 + 15) / 16) * 16; // ull[N*M]
constexpr size_t OFF_ZERO_END = OFF_BPK + (size_t)N * M * 8;   // zeroed each launch
constexpr size_t OFF_BTO   = ((OFF_ZERO_END + 15) / 16) * 16;  // float[N*P]
constexpr size_t OFF_BTI   = OFF_BTO + (size_t)N * P * 4;      // int[N*P]
constexpr size_t OFF_MINED = OFF_BTI + (size_t)N * P * 4;      // float[N*P]
constexpr size_t WS_NEEDED = OFF_MINED + (size_t)N * P * 4;

__device__ __forceinline__ float smooth_l1(float d) {
    float a = fabsf(d);
    return (a < 1.0f) ? 0.5f * d * d : (a - 0.5f);
}

// Kernel A: per-(n,p) jaccard vs all truths; best-truth per prior (registers);
// best-prior per truth via two-phase LDS max (value then index) + filtered
// global u64 atomicMax. All filters are exact because the maxima are monotone
// non-decreasing and 32/64-bit aligned loads are single instructions (no tear).
__global__ __launch_bounds__(256) void k_match(
    const float* __restrict__ priors, const float* __restrict__ targets,
    float* __restrict__ bto, int* __restrict__ bti,
    unsigned long long* __restrict__ bpk) {
    const int n = blockIdx.y;
    const int tid = threadIdx.x;
    const int p = blockIdx.x * 256 + tid;
    __shared__ float st[M * 5];
    __shared__ float sarea[M];
    __shared__ unsigned int sbp_ov[M];   // max float-bits of ov per truth (block)
    __shared__ unsigned int sbp_idx[M];  // min prior index among ties (block)
    if (tid < M * 5) st[tid] = targets[(size_t)n * M * 5 + tid];
    if (tid < M) { sbp_ov[tid] = 0u; sbp_idx[tid] = 0xFFFFFFFFu; }
    __syncthreads();
    if (tid < M) {
        sarea[tid] = (st[tid * 5 + 2] - st[tid * 5 + 0]) *
                     (st[tid * 5 + 3] - st[tid * 5 + 1]);
    }
    __syncthreads();

    const bool active = p < P;
    float ovs[M];
    float bestv = -1.0f;
    int bestm = 0;
    if (active) {
        float4 pr = reinterpret_cast<const float4*>(priors)[p];
        float bx1 = pr.x - pr.z * 0.5f, by1 = pr.y - pr.w * 0.5f;
        float bx2 = pr.x + pr.z * 0.5f, by2 = pr.y + pr.w * 0.5f;
        float area_b = (bx2 - bx1) * (by2 - by1);
        #pragma unroll
        for (int m = 0; m < M; ++m) {
            float tx1 = st[m * 5 + 0], ty1 = st[m * 5 + 1];
            float tx2 = st[m * 5 + 2], ty2 = st[m * 5 + 3];
            float ix = fmaxf(fminf(tx2, bx2) - fmaxf(tx1, bx1), 0.0f);
            float iy = fmaxf(fminf(ty2, by2) - fmaxf(ty1, by1), 0.0f);
            float inter = ix * iy;
            float ov = inter / (sarea[m] + area_b - inter);
            ovs[m] = ov;
            if (ov > bestv) { bestv = ov; bestm = m; }  // first-index tie-break
            // Phase 1: block max of ov bits (ov >= 0 so bits order == value order).
            unsigned int bits = __float_as_uint(ov);
            if (bits > sbp_ov[m]) atomicMax(&sbp_ov[m], bits);
        }
        bto[(size_t)n * P + p] = bestv;
        bti[(size_t)n * P + p] = bestm;
    }
    __syncthreads();
    if (active) {
        // Phase 2: exact smallest prior index among block-max ties.
        #pragma unroll
        for (int m = 0; m < M; ++m) {
            if (__float_as_uint(ovs[m]) == sbp_ov[m])
                atomicMin(&sbp_idx[m], (unsigned)p);
        }
    }
    __syncthreads();
    if (tid < M) {
        unsigned long long key =
            ((unsigned long long)sbp_ov[tid] << 32) |
            (unsigned long long)(0xFFFFFFFFu - sbp_idx[tid]);
        unsigned long long* dst = &bpk[(size_t)n * M + tid];
        if (key > *dst) atomicMax(dst, key);  // filtered; monotone => exact
    }
}

// Kernel B: force each truth's best prior to be a positive match; last write (highest m) wins
// to match numpy duplicate-index assignment semantics.
__global__ void k_force(float* __restrict__ bto, int* __restrict__ bti,
                        const unsigned long long* __restrict__ bpk) {
    int n = threadIdx.x;
    if (n < N) {
        for (int m = 0; m < M; ++m) {
            unsigned int low = (unsigned int)(bpk[(size_t)n * M + m] & 0xFFFFFFFFull);
            int bp = (int)(0xFFFFFFFFu - low);
            bto[(size_t)n * P + bp] = 2.0f;
            bti[(size_t)n * P + bp] = m;
        }
    }
}

// Kernel C: encode + smooth-L1 (pos-masked), logsumexp, conf loss, mined values,
// per-row num_pos and sum-of-pos conf loss, global loc loss.
__global__ __launch_bounds__(256) void k_loss(
    const float* __restrict__ loc, const float* __restrict__ conf,
    const float* __restrict__ priors, const float* __restrict__ targets,
    const float* __restrict__ bto, const int* __restrict__ bti,
    float* __restrict__ mined, double* __restrict__ loss_l_acc,
    int* __restrict__ num_pos, float* __restrict__ s_pos) {
    const int n = blockIdx.y;
    const int p0 = blockIdx.x * 256;
    const int tid = threadIdx.x;
    __shared__ float sc[256 * C];
    __shared__ float st[M * 5];
    __shared__ float wll[4], wsp[4];
    __shared__ int wnp[4];

    {   // coalesced stage of this block's conf tile
        const float* src = conf + (size_t)n * P * C + (size_t)p0 * C;
        int cnt = min(256, P - p0) * C;
        for (int i = tid; i < cnt; i += 256) sc[i] = src[i];
    }
    if (tid < M * 5) st[tid] = targets[(size_t)n * M * 5 + tid];
    __syncthreads();

    float my_ll = 0.0f, my_sp = 0.0f;
    int my_np = 0;
    const int p = p0 + tid;
    if (p < P) {
        float ov = bto[(size_t)n * P + p];
        int bt = bti[(size_t)n * P + p];
        bool pos = !(ov < THRESH);
        float mx1 = st[bt * 5 + 0], my1 = st[bt * 5 + 1];
        float mx2 = st[bt * 5 + 2], my2 = st[bt * 5 + 3];
        int conf_t = pos ? ((int)st[bt * 5 + 4] + 1) : 0;

        if (pos) {
            float4 pr = reinterpret_cast<const float4*>(priors)[p];
            float gcx = ((mx1 + mx2) * 0.5f - pr.x) / (0.1f * pr.z);
            float gcy = ((my1 + my2) * 0.5f - pr.y) / (0.1f * pr.w);
            float gw = logf((mx2 - mx1) / pr.z) / 0.2f;
            float gh = logf((my2 - my1) / pr.w) / 0.2f;
            float4 ld = reinterpret_cast<const float4*>(loc)[(size_t)n * P + p];
            my_ll = smooth_l1(ld.x - gcx) + smooth_l1(ld.y - gcy) +
                    smooth_l1(ld.z - gw) + smooth_l1(ld.w - gh);
            my_np = 1;
        }
        // logsumexp over 21 classes (max-shifted)
        float cv[C];
        #pragma unroll
        for (int c = 0; c < C; ++c) cv[c] = sc[tid * C + c];
        float mx = cv[0];
        #pragma unroll
        for (int c = 1; c < C; ++c) mx = fmaxf(mx, cv[c]);
        float s = 0.0f;
        #pragma unroll
        for (int c = 0; c < C; ++c) s += expf(cv[c] - mx);
        float lse = mx + logf(s);
        float lc = lse - cv[conf_t];
        if (pos) my_sp = lc;
        mined[(size_t)n * P + p] = pos ? 0.0f : lc;
    }

    // block reduce
    for (int off = 32; off > 0; off >>= 1) {
        my_ll += __shfl_down(my_ll, off);
        my_sp += __shfl_down(my_sp, off);
        my_np += __shfl_down(my_np, off);
    }
    int wave = tid >> 6, lane = tid & 63;
    if (lane == 0) { wll[wave] = my_ll; wsp[wave] = my_sp; wnp[wave] = my_np; }
    __syncthreads();
    if (tid == 0) {
        float ll = wll[0] + wll[1] + wll[2] + wll[3];
        float sp = wsp[0] + wsp[1] + wsp[2] + wsp[3];
        int np_ = wnp[0] + wnp[1] + wnp[2] + wnp[3];
        if (ll != 0.0f) atomicAdd(loss_l_acc, (double)ll);
        if (np_) atomicAdd(&num_pos[n], np_);
        if (sp != 0.0f) atomicAdd(&s_pos[n], sp);
    }
}

// Kernel D: per row, K = min(3*num_pos, P-1); T = K-th largest mined (radix select on
// float bits, valid since mined >= 0); loss_c_row = s_pos + sum(mined>T) + (K - cnt>T)*T.
__global__ __launch_bounds__(256) void k_select(
    const float* __restrict__ mined, const int* __restrict__ num_pos,
    const float* __restrict__ s_pos, float* __restrict__ lcrow) {
    const int n = blockIdx.x;
    const int tid = threadIdx.x;
    const float* row = mined + (size_t)n * P;
    __shared__ unsigned int hist[256];
    __shared__ unsigned int s_prefix;
    __shared__ int s_remK;
    __shared__ float wsg[4];
    __shared__ int wcg[4];

    const int K = min(3 * num_pos[n], P - 1);
    if (K <= 0) {
        if (tid == 0) lcrow[n] = s_pos[n];
        return;
    }
    unsigned int prefix = 0;
    int remK = K;
    for (int pass = 0; pass < 4; ++pass) {
        const int shift = 24 - pass * 8;
        hist[tid] = 0;
        __syncthreads();
        const unsigned int himask = (pass == 0) ? 0u : (0xFFFFFFFFu << (shift + 8));
        for (int i = tid; i < P; i += 256) {
            unsigned int key = __float_as_uint(row[i]);
            if ((key & himask) == prefix)
                atomicAdd(&hist[(key >> shift) & 0xFFu], 1u);
        }
        __syncthreads();
        if (tid == 0) {
            unsigned int cum = 0;
            int b = 255;
            for (; b >= 0; --b) {
                unsigned int c = hist[b];
                if (cum + c >= (unsigned)remK) break;
                cum += c;
            }
            if (b < 0) b = 0;  // defensive; invariant guarantees b >= 0
            s_prefix = prefix | ((unsigned)b << shift);
            s_remK = remK - (int)cum;
        }
        __syncthreads();
        prefix = s_prefix;
        remK = s_remK;
        __syncthreads();
    }
    const float T = __uint_as_float(prefix);
    float sgt = 0.0f;
    int cgt = 0;
    for (int i = tid; i < P; i += 256) {
        float v = row[i];
        if (v > T) { sgt += v; cgt++; }
    }
    for (int off = 32; off > 0; off >>= 1) {
        sgt += __shfl_down(sgt, off);
        cgt += __shfl_down(cgt, off);
    }
    int wave = tid >> 6, lane = tid & 63;
    if (lane == 0) { wsg[wave] = sgt; wcg[wave] = cgt; }
    __syncthreads();
    if (tid == 0) {
        float S = wsg[0] + wsg[1] + wsg[2] + wsg[3];
        int Cg = wcg[0] + wcg[1] + wcg[2] + wcg[3];
        lcrow[n] = s_pos[n] + S + (float)(K - Cg) * T;
    }
}

// Kernel E: finalize.
__global__ void k_final(const double* __restrict__ loss_l_acc,
                        const int* __restrict__ num_pos,
                        const float* __restrict__ lcrow,
                        float* __restrict__ out) {
    int t = threadIdx.x;  // 64 threads = 1 wave
    int npv = num_pos[t];
    float lcv = lcrow[t];
    for (int off = 32; off > 0; off >>= 1) {
        npv += __shfl_down(npv, off);
        lcv += __shfl_down(lcv, off);
    }
    if (t == 0) {
        float nf = (float)npv;
        out[0] = (float)(*loss_l_acc) / nf;
        out[1] = lcv / nf;
    }
}

extern "C" void kernel_launch(void* const* d_in, const int* in_sizes, int n_in,
                              void* d_out, int out_size, void* d_ws, size_t ws_size,
                              hipStream_t stream) {
    const float* loc = (const float*)d_in[0];
    const float* conf = (const float*)d_in[1];
    const float* priors = (const float*)d_in[2];
    const float* targets = (const float*)d_in[3];

    if (ws_size < WS_NEEDED) return;  // workspace too small; fail loudly at validation

    char* ws = (char*)d_ws;
    double* loss_l_acc = (double*)(ws + OFF_LOSS_L);
    int* num_pos = (int*)(ws + OFF_NUMPOS);
    float* s_pos = (float*)(ws + OFF_SPOS);
    float* lcrow = (float*)(ws + OFF_LCROW);
    unsigned long long* bpk = (unsigned long long*)(ws + OFF_BPK);
    float* bto = (float*)(ws + OFF_BTO);
    int* bti = (int*)(ws + OFF_BTI);
    float* mined = (float*)(ws + OFF_MINED);

    hipMemsetAsync(ws, 0, OFF_ZERO_END, stream);

    dim3 grid((P + 255) / 256, N);
    k_match<<<grid, 256, 0, stream>>>(priors, targets, bto, bti, bpk);
    k_force<<<1, 64, 0, stream>>>(bto, bti, bpk);
    k_loss<<<grid, 256, 0, stream>>>(loc, conf, priors, targets, bto, bti,
                                     mined, loss_l_acc, num_pos, s_pos);
    k_select<<<N, 256, 0, stream>>>(mined, num_pos, s_pos, lcrow);
    k_final<<<1, 64, 0, stream>>>(loss_l_acc, num_pos, lcrow, (float*)d_out);
}

// Round 3
// 317.993 us; speedup vs baseline: 2.2601x; 1.3445x over previous
//
#include <hip/hip_runtime.h>
#include <math.h>

// Problem constants (match setup_inputs)
constexpr int N = 64;
constexpr int P = 24564;
constexpr int M = 16;
constexpr int C = 21;
constexpr float THRESH = 0.5f;

// ---- workspace layout (bytes) ----
// zeroed each launch:
constexpr size_t OFF_SLL  = 0;                          // float[N] loc loss per row
constexpr size_t OFF_SPOS = OFF_SLL + (size_t)N * 4;    // float[N] pos conf loss per row
constexpr size_t OFF_NP   = OFF_SPOS + (size_t)N * 4;   // int[N]   num_pos per row
constexpr size_t OFF_BPK  = ((OFF_NP + (size_t)N * 4 + 15) / 16) * 16; // ull[N*M]
constexpr size_t OFF_ZEND = OFF_BPK + (size_t)N * M * 8;
// not zeroed:
constexpr size_t OFF_LCROW = ((OFF_ZEND + 15) / 16) * 16;               // float[N]
constexpr size_t OFF_MINED = ((OFF_LCROW + (size_t)N * 4 + 15) / 16) * 16; // float[N*P]
constexpr size_t WS_NEEDED = OFF_MINED + (size_t)N * P * 4;

__device__ __forceinline__ float smooth_l1(float d) {
    float a = fabsf(d);
    return (a < 1.0f) ? 0.5f * d * d : (a - 0.5f);
}

// Kernel A: per-(n,p) jaccard vs all truths; ONLY produces per-truth best-prior
// packed keys (bpk). Two-phase LDS max (value then min index) + filtered global
// u64 atomicMax. Filters are exact: maxima are monotone, aligned loads don't tear.
__global__ __launch_bounds__(256) void k_match(
    const float* __restrict__ priors, const float* __restrict__ targets,
    unsigned long long* __restrict__ bpk) {
    const int n = blockIdx.y;
    const int tid = threadIdx.x;
    const int p = blockIdx.x * 256 + tid;
    __shared__ float st[M * 5];
    __shared__ unsigned int sbp_ov[M];   // block max of ov float-bits per truth
    __shared__ unsigned int sbp_idx[M];  // min prior index among block-max ties
    if (tid < M * 5) st[tid] = targets[(size_t)n * M * 5 + tid];
    if (tid < M) { sbp_ov[tid] = 0u; sbp_idx[tid] = 0xFFFFFFFFu; }
    __syncthreads();

    const bool active = p < P;
    float ovs[M];
    if (active) {
        float4 pr = reinterpret_cast<const float4*>(priors)[p];
        float bx1 = pr.x - pr.z * 0.5f, by1 = pr.y - pr.w * 0.5f;
        float bx2 = pr.x + pr.z * 0.5f, by2 = pr.y + pr.w * 0.5f;
        float area_b = (bx2 - bx1) * (by2 - by1);
        #pragma unroll
        for (int m = 0; m < M; ++m) {
            float tx1 = st[m * 5 + 0], ty1 = st[m * 5 + 1];
            float tx2 = st[m * 5 + 2], ty2 = st[m * 5 + 3];
            float ix = fmaxf(fminf(tx2, bx2) - fmaxf(tx1, bx1), 0.0f);
            float iy = fmaxf(fminf(ty2, by2) - fmaxf(ty1, by1), 0.0f);
            float inter = ix * iy;
            float area_a = (tx2 - tx1) * (ty2 - ty1);
            float ov = inter / (area_a + area_b - inter);
            ovs[m] = ov;
            unsigned int bits = __float_as_uint(ov);  // ov >= 0: bits order == value order
            if (bits > sbp_ov[m]) atomicMax(&sbp_ov[m], bits);
        }
    }
    __syncthreads();
    if (active) {
        #pragma unroll
        for (int m = 0; m < M; ++m) {
            if (__float_as_uint(ovs[m]) == sbp_ov[m])
                atomicMin(&sbp_idx[m], (unsigned)p);
        }
    }
    __syncthreads();
    if (tid < M) {
        unsigned long long key =
            ((unsigned long long)sbp_ov[tid] << 32) |
            (unsigned long long)(0xFFFFFFFFu - sbp_idx[tid]);
        unsigned long long* dst = &bpk[(size_t)n * M + tid];
        if (key > *dst) atomicMax(dst, key);  // filtered; monotone => exact
    }
}

// Kernel B: recompute per-prior best truth, apply force-match from bpk inline
// (ascending m => last-write-wins, numpy duplicate-index semantics), then
// encode + smooth-L1 (pos-masked), logsumexp, mined values, per-row accumulators.
__global__ __launch_bounds__(256) void k_loss(
    const float* __restrict__ loc, const float* __restrict__ conf,
    const float* __restrict__ priors, const float* __restrict__ targets,
    const unsigned long long* __restrict__ bpk,
    float* __restrict__ mined, float* __restrict__ s_ll,
    int* __restrict__ num_pos, float* __restrict__ s_pos) {
    const int n = blockIdx.y;
    const int p0 = blockIdx.x * 256;
    const int tid = threadIdx.x;
    __shared__ __align__(16) float sc[256 * C];
    __shared__ float st[M * 5];
    __shared__ unsigned int fprior[M];
    __shared__ float wll[4], wsp[4];
    __shared__ int wnp[4];

    {   // vectorized coalesced stage of this block's conf tile (tile*C always %4==0)
        const float4* src4 = reinterpret_cast<const float4*>(
            conf + (size_t)n * P * C + (size_t)p0 * C);
        float4* sc4 = reinterpret_cast<float4*>(sc);
        int cnt4 = (min(256, P - p0) * C) >> 2;
        for (int i = tid; i < cnt4; i += 256) sc4[i] = src4[i];
    }
    if (tid < M * 5) st[tid] = targets[(size_t)n * M * 5 + tid];
    if (tid < M)
        fprior[tid] = 0xFFFFFFFFu -
                      (unsigned int)(bpk[(size_t)n * M + tid] & 0xFFFFFFFFull);
    __syncthreads();

    float my_ll = 0.0f, my_sp = 0.0f;
    int my_np = 0;
    const int p = p0 + tid;
    if (p < P) {
        float4 pr = reinterpret_cast<const float4*>(priors)[p];
        float bx1 = pr.x - pr.z * 0.5f, by1 = pr.y - pr.w * 0.5f;
        float bx2 = pr.x + pr.z * 0.5f, by2 = pr.y + pr.w * 0.5f;
        float area_b = (bx2 - bx1) * (by2 - by1);
        float bestv = -1.0f;
        int bestm = 0;
        #pragma unroll
        for (int m = 0; m < M; ++m) {
            float tx1 = st[m * 5 + 0], ty1 = st[m * 5 + 1];
            float tx2 = st[m * 5 + 2], ty2 = st[m * 5 + 3];
            float ix = fmaxf(fminf(tx2, bx2) - fmaxf(tx1, bx1), 0.0f);
            float iy = fmaxf(fminf(ty2, by2) - fmaxf(ty1, by1), 0.0f);
            float inter = ix * iy;
            float area_a = (tx2 - tx1) * (ty2 - ty1);
            float ov = inter / (area_a + area_b - inter);
            if (ov > bestv) { bestv = ov; bestm = m; }  // first-index tie-break
        }
        // force-match overrides (ascending m: last wins)
        #pragma unroll
        for (int m = 0; m < M; ++m) {
            if (fprior[m] == (unsigned)p) { bestv = 2.0f; bestm = m; }
        }
        bool pos = !(bestv < THRESH);
        float mx1 = st[bestm * 5 + 0], my1 = st[bestm * 5 + 1];
        float mx2 = st[bestm * 5 + 2], my2 = st[bestm * 5 + 3];
        int conf_t = pos ? ((int)st[bestm * 5 + 4] + 1) : 0;

        if (pos) {
            float gcx = ((mx1 + mx2) * 0.5f - pr.x) / (0.1f * pr.z);
            float gcy = ((my1 + my2) * 0.5f - pr.y) / (0.1f * pr.w);
            float gw = logf((mx2 - mx1) / pr.z) / 0.2f;
            float gh = logf((my2 - my1) / pr.w) / 0.2f;
            float4 ld = reinterpret_cast<const float4*>(loc)[(size_t)n * P + p];
            my_ll = smooth_l1(ld.x - gcx) + smooth_l1(ld.y - gcy) +
                    smooth_l1(ld.z - gw) + smooth_l1(ld.w - gh);
            my_np = 1;
        }
        // logsumexp over 21 classes (static-indexed regs; gather via one LDS read)
        float cv[C];
        #pragma unroll
        for (int c = 0; c < C; ++c) cv[c] = sc[tid * C + c];
        float mx = cv[0];
        #pragma unroll
        for (int c = 1; c < C; ++c) mx = fmaxf(mx, cv[c]);
        float s = 0.0f;
        #pragma unroll
        for (int c = 0; c < C; ++c) s += expf(cv[c] - mx);
        float gathered = sc[tid * C + conf_t];
        float lc = mx + logf(s) - gathered;
        if (pos) my_sp = lc;
        mined[(size_t)n * P + p] = pos ? 0.0f : lc;
    }

    // block reduce (lane 0 of each wave holds valid partial)
    for (int off = 32; off > 0; off >>= 1) {
        my_ll += __shfl_down(my_ll, off);
        my_sp += __shfl_down(my_sp, off);
        my_np += __shfl_down(my_np, off);
    }
    int wave = tid >> 6, lane = tid & 63;
    if (lane == 0) { wll[wave] = my_ll; wsp[wave] = my_sp; wnp[wave] = my_np; }
    __syncthreads();
    if (tid == 0) {
        float ll = wll[0] + wll[1] + wll[2] + wll[3];
        float sp = wsp[0] + wsp[1] + wsp[2] + wsp[3];
        int np_ = wnp[0] + wnp[1] + wnp[2] + wnp[3];
        if (ll != 0.0f) atomicAdd(&s_ll[n], ll);
        if (np_) atomicAdd(&num_pos[n], np_);
        if (sp != 0.0f) atomicAdd(&s_pos[n], sp);
    }
}

// Kernel C: per row, K = min(3*num_pos, P-1); T = K-th largest mined via 4-pass
// 8-bit radix select (float bits, valid since mined >= 0).
// loss_c_row = s_pos + sum(mined>T) + (K - cnt>T)*T.
// 1024 threads; per-wave privatized histograms; wave-parallel suffix scan.
__global__ __launch_bounds__(1024) void k_select(
    const float* __restrict__ mined, const int* __restrict__ num_pos,
    const float* __restrict__ s_pos, float* __restrict__ lcrow) {
    const int n = blockIdx.x;
    const int tid = threadIdx.x;
    const int wid = tid >> 6, lane = tid & 63;
    const float4* row4 = reinterpret_cast<const float4*>(mined + (size_t)n * P);
    constexpr int P4 = P / 4;  // 6141 exact

    __shared__ unsigned int whist[16 * 256];
    __shared__ unsigned int hist[256];
    __shared__ unsigned int suf[256];
    __shared__ unsigned int s_prefix;
    __shared__ int s_remK;
    __shared__ float wsg[16];
    __shared__ int wcg[16];

    const int K = min(3 * num_pos[n], P - 1);
    if (K <= 0) {  // block-uniform early exit
        if (tid == 0) lcrow[n] = s_pos[n];
        return;
    }

    unsigned int prefix = 0;
    int remK = K;
    for (int pass = 0; pass < 4; ++pass) {
        const int shift = 24 - pass * 8;
        const unsigned int himask = (pass == 0) ? 0u : (0xFFFFFFFFu << (shift + 8));
        for (int i = tid; i < 16 * 256; i += 1024) whist[i] = 0;
        __syncthreads();
        unsigned int* mh = &whist[wid * 256];
        for (int i = tid; i < P4; i += 1024) {
            float4 v = row4[i];
            unsigned int k0 = __float_as_uint(v.x), k1 = __float_as_uint(v.y);
            unsigned int k2 = __float_as_uint(v.z), k3 = __float_as_uint(v.w);
            if ((k0 & himask) == prefix) atomicAdd(&mh[(k0 >> shift) & 255u], 1u);
            if ((k1 & himask) == prefix) atomicAdd(&mh[(k1 >> shift) & 255u], 1u);
            if ((k2 & himask) == prefix) atomicAdd(&mh[(k2 >> shift) & 255u], 1u);
            if ((k3 & himask) == prefix) atomicAdd(&mh[(k3 >> shift) & 255u], 1u);
        }
        __syncthreads();
        if (tid < 256) {
            unsigned int h = 0;
            #pragma unroll
            for (int w = 0; w < 16; ++w) h += whist[w * 256 + tid];
            hist[tid] = h;
        }
        __syncthreads();
        if (tid < 64) {  // wave 0: suffix sums of 256 bins, 4 bins/lane
            unsigned int h0 = hist[tid * 4 + 0], h1 = hist[tid * 4 + 1];
            unsigned int h2 = hist[tid * 4 + 2], h3 = hist[tid * 4 + 3];
            unsigned int s3 = h3, s2 = h2 + s3, s1 = h1 + s2, s0 = h0 + s1;
            unsigned int tot = s0;
            #pragma unroll
            for (int off = 1; off < 64; off <<= 1) {
                unsigned int v = __shfl_down(tot, off);
                if (lane + off < 64) tot += v;
            }
            unsigned int above = tot - s0;  // sum of groups with index > lane
            suf[tid * 4 + 0] = above + s0;
            suf[tid * 4 + 1] = above + s1;
            suf[tid * 4 + 2] = above + s2;
            suf[tid * 4 + 3] = above + s3;
        }
        __syncthreads();
        if (tid < 256) {
            unsigned int Sb = suf[tid];
            unsigned int Sb1 = (tid == 255) ? 0u : suf[tid + 1];
            if (Sb >= (unsigned)remK && Sb1 < (unsigned)remK) {  // unique bin
                s_prefix = prefix | ((unsigned)tid << shift);
                s_remK = remK - (int)Sb1;
            }
        }
        __syncthreads();
        prefix = s_prefix;
        remK = s_remK;
        __syncthreads();
    }
    const float T = __uint_as_float(prefix);
    float sgt = 0.0f;
    int cgt = 0;
    for (int i = tid; i < P4; i += 1024) {
        float4 v = row4[i];
        if (v.x > T) { sgt += v.x; cgt++; }
        if (v.y > T) { sgt += v.y; cgt++; }
        if (v.z > T) { sgt += v.z; cgt++; }
        if (v.w > T) { sgt += v.w; cgt++; }
    }
    for (int off = 32; off > 0; off >>= 1) {
        sgt += __shfl_down(sgt, off);
        cgt += __shfl_down(cgt, off);
    }
    if (lane == 0) { wsg[wid] = sgt; wcg[wid] = cgt; }
    __syncthreads();
    if (tid == 0) {
        float S = 0.0f;
        int Cg = 0;
        #pragma unroll
        for (int w = 0; w < 16; ++w) { S += wsg[w]; Cg += wcg[w]; }
        lcrow[n] = s_pos[n] + S + (float)(K - Cg) * T;
    }
}

// Kernel D: finalize.
__global__ void k_final(const float* __restrict__ s_ll,
                        const int* __restrict__ num_pos,
                        const float* __restrict__ lcrow,
                        float* __restrict__ out) {
    int t = threadIdx.x;  // 64 threads = 1 wave
    float llv = s_ll[t];
    int npv = num_pos[t];
    float lcv = lcrow[t];
    for (int off = 32; off > 0; off >>= 1) {
        llv += __shfl_down(llv, off);
        npv += __shfl_down(npv, off);
        lcv += __shfl_down(lcv, off);
    }
    if (t == 0) {
        float nf = (float)npv;
        out[0] = llv / nf;
        out[1] = lcv / nf;
    }
}

extern "C" void kernel_launch(void* const* d_in, const int* in_sizes, int n_in,
                              void* d_out, int out_size, void* d_ws, size_t ws_size,
                              hipStream_t stream) {
    const float* loc = (const float*)d_in[0];
    const float* conf = (const float*)d_in[1];
    const float* priors = (const float*)d_in[2];
    const float* targets = (const float*)d_in[3];

    if (ws_size < WS_NEEDED) return;  // workspace too small; fail loudly at validation

    char* ws = (char*)d_ws;
    float* s_ll = (float*)(ws + OFF_SLL);
    float* s_pos = (float*)(ws + OFF_SPOS);
    int* num_pos = (int*)(ws + OFF_NP);
    unsigned long long* bpk = (unsigned long long*)(ws + OFF_BPK);
    float* lcrow = (float*)(ws + OFF_LCROW);
    float* mined = (float*)(ws + OFF_MINED);

    hipMemsetAsync(ws, 0, OFF_ZEND, stream);

    dim3 grid((P + 255) / 256, N);
    k_match<<<grid, 256, 0, stream>>>(priors, targets, bpk);
    k_loss<<<grid, 256, 0, stream>>>(loc, conf, priors, targets, bpk,
                                     mined, s_ll, num_pos, s_pos);
    k_select<<<N, 1024, 0, stream>>>(mined, num_pos, s_pos, lcrow);
    k_final<<<1, 64, 0, stream>>>(s_ll, num_pos, lcrow, (float*)d_out);
}